// Round 3
// baseline (416.330 us; speedup 1.0000x reference)
//
#include <hip/hip_runtime.h>
#include <math.h>

typedef unsigned short u16;
typedef __attribute__((ext_vector_type(8))) short bf16x8;   // 8 bf16 = 4 VGPRs (MFMA A/B frag)
typedef __attribute__((ext_vector_type(4))) float f32x4;    // MFMA C/D frag

#define NB 1024          // graphs
#define NS 48            // nodes per graph
#define ND 256           // input dim
#define NN (NB*NS)       // 49152 nodes
#define NE (4*NN)        // 196608 edges
#define GD 512           // graph_dim
#define KD 512           // GEMM K (= 2*ND = GD)
#define NO 1024          // GEMM out cols (W_l ; W_r stacked)

__device__ __forceinline__ void gld16(const void* g, void* l) {
  // global -> LDS direct, 16B per lane; LDS dest = wave-uniform base + lane*16.
  // Real addrspacecast (direct C-style cast) — an integer round-trip keeps the
  // flat aperture address and faults.
  __builtin_amdgcn_global_load_lds(
      (const __attribute__((address_space(1))) void*)(void*)g,
      (__attribute__((address_space(3))) void*)l, 16, 0, 0);
}

__device__ __forceinline__ float bf2f(u16 h) {
  unsigned u = ((unsigned)h) << 16; float f; __builtin_memcpy(&f, &u, 4); return f;
}
__device__ __forceinline__ u16 f2bf(float f) {
  unsigned u; __builtin_memcpy(&u, &f, 4);
  u += 0x7fffu + ((u >> 16) & 1u);           // RNE
  return (u16)(u >> 16);
}
__device__ __forceinline__ void unpack8(uint4 v, float* f) {
  f[0]=bf2f((u16)(v.x & 0xffff)); f[1]=bf2f((u16)(v.x >> 16));
  f[2]=bf2f((u16)(v.y & 0xffff)); f[3]=bf2f((u16)(v.y >> 16));
  f[4]=bf2f((u16)(v.z & 0xffff)); f[5]=bf2f((u16)(v.z >> 16));
  f[6]=bf2f((u16)(v.w & 0xffff)); f[7]=bf2f((u16)(v.w >> 16));
}
__device__ __forceinline__ uint4 pack8(const float* f) {
  uint4 v;
  v.x = (unsigned)f2bf(f[0]) | ((unsigned)f2bf(f[1]) << 16);
  v.y = (unsigned)f2bf(f[2]) | ((unsigned)f2bf(f[3]) << 16);
  v.z = (unsigned)f2bf(f[4]) | ((unsigned)f2bf(f[5]) << 16);
  v.w = (unsigned)f2bf(f[6]) | ((unsigned)f2bf(f[7]) << 16);
  return v;
}

// ---------- graph preprocessing ----------
// edge_index arrives as INT32 on device (harness converts all integer inputs
// to int32) — reading it as int64 was the round-0/1 core dump.

__global__ void k_hist(const int* __restrict__ ei, int* __restrict__ deg, int* __restrict__ cnt) {
  int e = blockIdx.x * 256 + threadIdx.x;
  if (e < NE) {
    atomicAdd(&deg[ei[e]], 1);        // row = out histogram
    atomicAdd(&cnt[ei[NE + e]], 1);   // col = in  histogram
  }
}

__global__ void k_dinv(const int* __restrict__ deg, float* __restrict__ dinv) {
  int i = blockIdx.x * 256 + threadIdx.x;
  if (i < NN) dinv[i] = (deg[i] > 0) ? rsqrtf((float)deg[i]) : 0.0f;
}

// exclusive scan of NN ints, single block of 1024 threads, 48 elems/thread
__global__ void k_exscan(const int* __restrict__ in, int* __restrict__ out) {
  __shared__ int sums[1024];
  const int t = threadIdx.x;
  const int base = t * 48;
  int s = 0;
  for (int i = 0; i < 48; ++i) s += in[base + i];
  sums[t] = s;
  __syncthreads();
  for (int off = 1; off < 1024; off <<= 1) {
    int v = (t >= off) ? sums[t - off] : 0;
    __syncthreads();
    sums[t] += v;
    __syncthreads();
  }
  int run = (t == 0) ? 0 : sums[t - 1];
  for (int i = 0; i < 48; ++i) { int v = in[base + i]; out[base + i] = run; run += v; }
  if (t == 1023) out[NN] = run;
}

__global__ void k_fill(const int* __restrict__ ei,
                       const int* __restrict__ rowOff, const int* __restrict__ colOff,
                       int* __restrict__ rowFill, int* __restrict__ colFill,
                       int* __restrict__ rowCol, int* __restrict__ colSrc) {
  int e = blockIdx.x * 256 + threadIdx.x;
  if (e < NE) {
    int r = ei[e], c = ei[NE + e];
    int pr = atomicAdd(&rowFill[r], 1);
    rowCol[rowOff[r] + pr] = c;            // row-CSR: neighbors by src
    int pc = atomicAdd(&colFill[c], 1);
    colSrc[colOff[c] + pc] = r;            // col-CSR: sources by dst
  }
}

__global__ void k_wcat(const float* __restrict__ Wl, const float* __restrict__ Wr, u16* __restrict__ Wc) {
  int i = blockIdx.x * 256 + threadIdx.x;
  if (i < GD * KD) {
    Wc[i] = f2bf(Wl[i]);
    Wc[GD * KD + i] = f2bf(Wr[i]);
  }
}

// lap_x[i] = x[i] - dinv[i] * sum_{e: row=i} dinv[col_e] * x[col_e]; write xcomb=[x | lap] bf16
__global__ void k_lap(const float* __restrict__ x, const int* __restrict__ rowOff,
                      const int* __restrict__ rowCol, const float* __restrict__ dinv,
                      u16* __restrict__ xcomb) {
  const int gid = blockIdx.x * 256 + threadIdx.x;
  const int node = gid >> 6, lane = gid & 63;       // one wave per node, 4 feats/lane
  const float4 xi = *(const float4*)(x + (size_t)node * ND + lane * 4);
  float a0 = 0.f, a1 = 0.f, a2 = 0.f, a3 = 0.f;
  const int s0 = rowOff[node], s1 = rowOff[node + 1];
  for (int p = s0; p < s1; ++p) {
    const int c = rowCol[p];
    const float wgt = dinv[c];
    const float4 xc = *(const float4*)(x + (size_t)c * ND + lane * 4);
    a0 += wgt * xc.x; a1 += wgt * xc.y; a2 += wgt * xc.z; a3 += wgt * xc.w;
  }
  const float di = dinv[node];
  u16* dst = xcomb + (size_t)node * KD + lane * 4;
  ushort4 hx; hx.x = f2bf(xi.x); hx.y = f2bf(xi.y); hx.z = f2bf(xi.z); hx.w = f2bf(xi.w);
  *(ushort4*)dst = hx;
  ushort4 hl; hl.x = f2bf(xi.x - di * a0); hl.y = f2bf(xi.y - di * a1);
  hl.z = f2bf(xi.z - di * a2); hl.w = f2bf(xi.w - di * a3);
  *(ushort4*)(dst + ND) = hl;
}

// ---------- GEMM: O[N,1024] = A[N,512] @ Wcat[1024,512]^T, bf16 in/out, f32 accum ----------
// 128x128 tile, 4 waves (2x2 quadrants of 64x64), BK=32, global_load_lds staging (m97 structure)
__global__ __launch_bounds__(256) void k_gemm(const u16* __restrict__ A,
                                              const u16* __restrict__ Bw,
                                              u16* __restrict__ O) {
  __shared__ u16 As[128 * 32];
  __shared__ u16 Bs[128 * 32];
  const int tid = threadIdx.x;
  const int w = tid >> 6, lane = tid & 63;
  const int wr = w >> 1, wc = w & 1;
  const int bx = blockIdx.x, by = blockIdx.y;

  // staging: 8 chunks of 16 rows x 32 cols (1KB); wave w owns chunks 2w, 2w+1
  const int c0 = w * 2, c1 = c0 + 1;
  const int lrow = lane >> 2, lcol = (lane & 3) * 8;
  const u16* Ag0 = A + (size_t)(bx * 128 + c0 * 16 + lrow) * KD + lcol;
  const u16* Ag1 = A + (size_t)(bx * 128 + c1 * 16 + lrow) * KD + lcol;
  const u16* Bg0 = Bw + (size_t)(by * 128 + c0 * 16 + lrow) * KD + lcol;
  const u16* Bg1 = Bw + (size_t)(by * 128 + c1 * 16 + lrow) * KD + lcol;
  u16* As0 = As + c0 * 512; u16* As1 = As + c1 * 512;
  u16* Bs0 = Bs + c0 * 512; u16* Bs1 = Bs + c1 * 512;

  // fragment read offsets: row = quadrant + mi*16 + (lane&15), k = (lane>>4)*8
  const int aoff = (wr * 64 + (lane & 15)) * 32 + (lane >> 4) * 8;
  const int boff = (wc * 64 + (lane & 15)) * 32 + (lane >> 4) * 8;

  f32x4 acc[4][4] = {};

  for (int kt = 0; kt < KD; kt += 32) {
    gld16(Ag0 + kt, As0);
    gld16(Ag1 + kt, As1);
    gld16(Bg0 + kt, Bs0);
    gld16(Bg1 + kt, Bs1);
    __syncthreads();                       // drains vmcnt -> LDS tile ready
    bf16x8 aF[4], bF[4];
    #pragma unroll
    for (int i = 0; i < 4; ++i) aF[i] = *(const bf16x8*)(As + aoff + i * 512);
    #pragma unroll
    for (int i = 0; i < 4; ++i) bF[i] = *(const bf16x8*)(Bs + boff + i * 512);
    #pragma unroll
    for (int mi = 0; mi < 4; ++mi)
      #pragma unroll
      for (int ni = 0; ni < 4; ++ni)
        acc[mi][ni] = __builtin_amdgcn_mfma_f32_16x16x32_bf16(aF[mi], bF[ni], acc[mi][ni], 0, 0, 0);
    __syncthreads();                       // protect LDS before next overwrite
  }

  // C/D layout: col = lane&15, row = (lane>>4)*4 + r  [verified m89/m91]
  const int lc = lane & 15, lr = (lane >> 4) * 4;
  const size_t r0 = (size_t)bx * 128 + wr * 64;
  const int cbase = by * 128 + wc * 64;
  #pragma unroll
  for (int mi = 0; mi < 4; ++mi)
    #pragma unroll
    for (int ni = 0; ni < 4; ++ni)
      #pragma unroll
      for (int r = 0; r < 4; ++r)
        O[(r0 + mi * 16 + lr + r) * NO + (cbase + ni * 16 + lc)] = f2bf(acc[mi][ni][r]);
}

// h = gelu(mean_{col-CSR}(P1) + R1 + b1); P1 = O1[:, :512], R1 = O1[:, 512:]
__global__ void k_agg1(const u16* __restrict__ O1, const int* __restrict__ colOff,
                       const int* __restrict__ colSrc, const float* __restrict__ b1,
                       u16* __restrict__ h) {
  const int gid = blockIdx.x * 256 + threadIdx.x;
  const int node = gid >> 6, lane = gid & 63;       // one wave per node, 8 feats/lane
  const int f0 = lane * 8;
  float acc[8] = {};
  const int s0 = colOff[node], s1 = colOff[node + 1];
  for (int p = s0; p < s1; ++p) {
    const int src = colSrc[p];
    const uint4 v = *(const uint4*)(O1 + (size_t)src * NO + f0);
    float tmp[8]; unpack8(v, tmp);
    #pragma unroll
    for (int j = 0; j < 8; ++j) acc[j] += tmp[j];
  }
  const float inv = (s1 > s0) ? 1.0f / (float)(s1 - s0) : 1.0f;
  const uint4 rv = *(const uint4*)(O1 + (size_t)node * NO + GD + f0);
  float rr[8]; unpack8(rv, rr);
  float res[8];
  #pragma unroll
  for (int j = 0; j < 8; ++j) {
    float v = acc[j] * inv + rr[j] + b1[f0 + j];
    res[j] = 0.5f * v * (1.0f + erff(v * 0.70710678118654752f));   // exact gelu
  }
  *(uint4*)(h + (size_t)node * GD + f0) = pack8(res);
}

// pooled[g] = mean_s( mean_{col-CSR}(P2) + R2 ) + b2
__global__ void k_agg2pool(const u16* __restrict__ O2, const int* __restrict__ colOff,
                           const int* __restrict__ colSrc, const float* __restrict__ b2,
                           float* __restrict__ out) {
  const int g = blockIdx.x;
  const int t = threadIdx.x;                         // 256 threads, 2 feats/thread
  const int f0 = t * 2;
  float p0 = 0.f, p1 = 0.f;
  for (int s = 0; s < NS; ++s) {
    const int node = g * NS + s;
    const int s0 = colOff[node], s1 = colOff[node + 1];
    float a0 = 0.f, a1 = 0.f;
    for (int p = s0; p < s1; ++p) {
      const int src = colSrc[p];
      const unsigned v = *(const unsigned*)(O2 + (size_t)src * NO + f0);
      a0 += bf2f((u16)(v & 0xffff)); a1 += bf2f((u16)(v >> 16));
    }
    const float inv = (s1 > s0) ? 1.0f / (float)(s1 - s0) : 1.0f;
    const unsigned rv = *(const unsigned*)(O2 + (size_t)node * NO + GD + f0);
    p0 += a0 * inv + bf2f((u16)(rv & 0xffff));
    p1 += a1 * inv + bf2f((u16)(rv >> 16));
  }
  const float invS = 1.0f / (float)NS;
  out[(size_t)g * GD + f0]     = p0 * invS + b2[f0];
  out[(size_t)g * GD + f0 + 1] = p1 * invS + b2[f0 + 1];
}

extern "C" void kernel_launch(void* const* d_in, const int* in_sizes, int n_in,
                              void* d_out, int out_size, void* d_ws, size_t ws_size,
                              hipStream_t stream) {
  const float* x   = (const float*)d_in[0];
  const int*   ei  = (const int*)d_in[1];           // int64 in reference -> int32 on device
  const float* Wl1 = (const float*)d_in[2];
  const float* Wr1 = (const float*)d_in[3];
  const float* b1  = (const float*)d_in[4];
  const float* Wl2 = (const float*)d_in[5];
  const float* Wr2 = (const float*)d_in[6];
  const float* b2  = (const float*)d_in[7];
  float* out = (float*)d_out;
  (void)in_sizes; (void)n_in; (void)out_size; (void)ws_size;

  // ---- workspace layout (all segments multiples of 256B) ----
  int* deg     = (int*)d_ws;              // NN
  int* cnt     = deg + NN;                // NN
  int* rowFill = cnt + NN;                // NN
  int* colFill = rowFill + NN;            // NN   (deg..colFill = one memset region)
  int* rowOff  = colFill + NN;            // NN+64
  int* colOff  = rowOff + NN + 64;        // NN+64
  float* dinv  = (float*)(colOff + NN + 64); // NN
  int* rowCol  = (int*)(dinv + NN);       // NE
  int* colSrc  = rowCol + NE;             // NE
  u16* Wc1     = (u16*)(colSrc + NE);     // NO*KD
  u16* Wc2     = Wc1 + (size_t)NO * KD;   // NO*KD
  u16* xcomb   = Wc2 + (size_t)NO * KD;   // NN*KD   (reused as h after GEMM1)
  u16* Obuf    = xcomb + (size_t)NN * KD; // NN*NO   (O1, reused as O2)
  u16* h       = xcomb;

  hipMemsetAsync(deg, 0, sizeof(int) * 4 * NN, stream);

  k_hist<<<NE / 256, 256, 0, stream>>>(ei, deg, cnt);
  k_dinv<<<NN / 256, 256, 0, stream>>>(deg, dinv);
  k_exscan<<<1, 1024, 0, stream>>>(deg, rowOff);
  k_exscan<<<1, 1024, 0, stream>>>(cnt, colOff);
  k_fill<<<NE / 256, 256, 0, stream>>>(ei, rowOff, colOff, rowFill, colFill, rowCol, colSrc);
  k_wcat<<<(GD * KD) / 256, 256, 0, stream>>>(Wl1, Wr1, Wc1);
  k_wcat<<<(GD * KD) / 256, 256, 0, stream>>>(Wl2, Wr2, Wc2);
  k_lap<<<(NN * 64) / 256, 256, 0, stream>>>(x, rowOff, rowCol, dinv, xcomb);

  dim3 gg(NN / 128, NO / 128);
  k_gemm<<<gg, 256, 0, stream>>>(xcomb, Wc1, Obuf);
  k_agg1<<<(NN * 64) / 256, 256, 0, stream>>>(Obuf, colOff, colSrc, b1, h);
  k_gemm<<<gg, 256, 0, stream>>>(h, Wc2, Obuf);
  k_agg2pool<<<NB, 256, 0, stream>>>(Obuf, colOff, colSrc, b2, out);
}

// Round 4
// 323.780 us; speedup vs baseline: 1.2858x; 1.2858x over previous
//
#include <hip/hip_runtime.h>
#include <math.h>

typedef unsigned short u16;
typedef __attribute__((ext_vector_type(8))) short bf16x8;   // 8 bf16 = 4 VGPRs (MFMA A/B frag)
typedef __attribute__((ext_vector_type(4))) float f32x4;    // MFMA C/D frag

#define NB 1024          // graphs
#define NS 48            // nodes per graph
#define ND 256           // input dim
#define NN (NB*NS)       // 49152 nodes
#define NE (4*NN)        // 196608 edges
#define GD 512           // graph_dim / feature stride everywhere

__device__ __forceinline__ void gld16(const void* g, void* l) {
  // global -> LDS direct, 16B per lane; LDS dest = wave-uniform base + lane*16.
  __builtin_amdgcn_global_load_lds(
      (const __attribute__((address_space(1))) void*)(void*)g,
      (__attribute__((address_space(3))) void*)l, 16, 0, 0);
}

__device__ __forceinline__ float bf2f(u16 h) {
  unsigned u = ((unsigned)h) << 16; float f; __builtin_memcpy(&f, &u, 4); return f;
}
__device__ __forceinline__ u16 f2bf(float f) {
  unsigned u; __builtin_memcpy(&u, &f, 4);
  u += 0x7fffu + ((u >> 16) & 1u);           // RNE
  return (u16)(u >> 16);
}
__device__ __forceinline__ void unpack8(uint4 v, float* f) {
  f[0]=bf2f((u16)(v.x & 0xffff)); f[1]=bf2f((u16)(v.x >> 16));
  f[2]=bf2f((u16)(v.y & 0xffff)); f[3]=bf2f((u16)(v.y >> 16));
  f[4]=bf2f((u16)(v.z & 0xffff)); f[5]=bf2f((u16)(v.z >> 16));
  f[6]=bf2f((u16)(v.w & 0xffff)); f[7]=bf2f((u16)(v.w >> 16));
}
__device__ __forceinline__ uint4 pack8(const float* f) {
  uint4 v;
  v.x = (unsigned)f2bf(f[0]) | ((unsigned)f2bf(f[1]) << 16);
  v.y = (unsigned)f2bf(f[2]) | ((unsigned)f2bf(f[3]) << 16);
  v.z = (unsigned)f2bf(f[4]) | ((unsigned)f2bf(f[5]) << 16);
  v.w = (unsigned)f2bf(f[6]) | ((unsigned)f2bf(f[7]) << 16);
  return v;
}

// ---------- graph preprocessing (edge_index = int32 on device) ----------

__global__ void k_hist(const int* __restrict__ ei, int* __restrict__ deg, int* __restrict__ cnt) {
  int e = blockIdx.x * 256 + threadIdx.x;
  if (e < NE) {
    atomicAdd(&deg[ei[e]], 1);        // out-degree (row)
    atomicAdd(&cnt[ei[NE + e]], 1);   // in-degree  (col)
  }
}

__global__ void k_dinv(const int* __restrict__ deg, float* __restrict__ dinv) {
  int i = blockIdx.x * 256 + threadIdx.x;
  if (i < NN) dinv[i] = (deg[i] > 0) ? rsqrtf((float)deg[i]) : 0.0f;
}

// exclusive scan of NN ints, single block of 1024 threads, 48 elems/thread
__global__ void k_exscan(const int* __restrict__ in, int* __restrict__ out) {
  __shared__ int sums[1024];
  const int t = threadIdx.x;
  const int base = t * 48;
  int s = 0;
  for (int i = 0; i < 48; ++i) s += in[base + i];
  sums[t] = s;
  __syncthreads();
  for (int off = 1; off < 1024; off <<= 1) {
    int v = (t >= off) ? sums[t - off] : 0;
    __syncthreads();
    sums[t] += v;
    __syncthreads();
  }
  int run = (t == 0) ? 0 : sums[t - 1];
  for (int i = 0; i < 48; ++i) { int v = in[base + i]; out[base + i] = run; run += v; }
  if (t == 1023) out[NN] = run;
}

__global__ void k_fill(const int* __restrict__ ei,
                       const int* __restrict__ rowOff, const int* __restrict__ colOff,
                       int* __restrict__ rowFill, int* __restrict__ colFill,
                       int* __restrict__ rowCol, int* __restrict__ colSrc) {
  int e = blockIdx.x * 256 + threadIdx.x;
  if (e < NE) {
    int r = ei[e], c = ei[NE + e];
    int pr = atomicAdd(&rowFill[r], 1);
    rowCol[rowOff[r] + pr] = c;            // row-CSR: dst list per src (Laplacian)
    int pc = atomicAdd(&colFill[c], 1);
    colSrc[colOff[c] + pc] = r;            // col-CSR: src list per dst (SAGE agg)
  }
}

// convert one [512,512] f32 weight to bf16; 4 elems/thread
__global__ void k_wcat(const float* __restrict__ W, u16* __restrict__ Wc) {
  int i = (blockIdx.x * 256 + threadIdx.x) * 4;
  float4 v = *(const float4*)(W + i);
  ushort4 h; h.x = f2bf(v.x); h.y = f2bf(v.y); h.z = f2bf(v.z); h.w = f2bf(v.w);
  *(ushort4*)(Wc + i) = h;
}

// lap_x[i] = x[i] - dinv[i] * sum_{row-CSR} dinv[c] * x[c]; write xc = [x | lap] bf16 [N,512]
__global__ void k_lap(const float* __restrict__ x, const int* __restrict__ rowOff,
                      const int* __restrict__ rowCol, const float* __restrict__ dinv,
                      u16* __restrict__ xc) {
  const int gid = blockIdx.x * 256 + threadIdx.x;
  const int node = gid >> 6, lane = gid & 63;       // one wave per node, 4 feats/lane
  const float4 xi = *(const float4*)(x + (size_t)node * ND + lane * 4);
  float a0 = 0.f, a1 = 0.f, a2 = 0.f, a3 = 0.f;
  const int s0 = rowOff[node], s1 = rowOff[node + 1];
  for (int p = s0; p < s1; ++p) {
    const int c = rowCol[p];
    const float wgt = dinv[c];
    const float4 v = *(const float4*)(x + (size_t)c * ND + lane * 4);
    a0 += wgt * v.x; a1 += wgt * v.y; a2 += wgt * v.z; a3 += wgt * v.w;
  }
  const float di = dinv[node];
  u16* dst = xc + (size_t)node * GD + lane * 4;
  ushort4 hx; hx.x = f2bf(xi.x); hx.y = f2bf(xi.y); hx.z = f2bf(xi.z); hx.w = f2bf(xi.w);
  *(ushort4*)dst = hx;
  ushort4 hl; hl.x = f2bf(xi.x - di * a0); hl.y = f2bf(xi.y - di * a1);
  hl.z = f2bf(xi.z - di * a2); hl.w = f2bf(xi.w - di * a3);
  *(ushort4*)(dst + ND) = hl;
}

// xagg[i] = (1/cnt_i) * sum_{src->i} xc[src]   (mean_agg commuted BEFORE the GEMM)
__global__ void k_aggx(const u16* __restrict__ xc, const int* __restrict__ colOff,
                       const int* __restrict__ colSrc, u16* __restrict__ xagg) {
  const int gid = blockIdx.x * 256 + threadIdx.x;
  const int node = gid >> 6, lane = gid & 63;       // one wave per node, 8 feats/lane
  const int f0 = lane * 8;
  float acc[8] = {};
  const int s0 = colOff[node], s1 = colOff[node + 1];
  for (int p = s0; p < s1; ++p) {
    float tmp[8]; unpack8(*(const uint4*)(xc + (size_t)colSrc[p] * GD + f0), tmp);
    #pragma unroll
    for (int j = 0; j < 8; ++j) acc[j] += tmp[j];
  }
  const float inv = (s1 > s0) ? 1.0f / (float)(s1 - s0) : 1.0f;
  float res[8];
  #pragma unroll
  for (int j = 0; j < 8; ++j) res[j] = acc[j] * inv;
  *(uint4*)(xagg + (size_t)node * GD + f0) = pack8(res);
}

// ---------- GEMM: Out[M,512] = A0@B0^T + A1@B1^T (+bias, +gelu), K=512+512 ----------
// A0/A1: [M,512] bf16; B0/B1: [512,512] bf16 (row = out col, contiguous K).
// 128x128 tile, 4 waves (2x2 quadrants of 64x64), BK=32, global_load_lds staging.
// Grid: (N/128, M/128) — N-dim fastest so blocks sharing an A-tile are launch-adjacent (L2 reuse).
// MODE 0: +bias, exact gelu, bf16 out.  MODE 1: +bias, f32 out.
template <int MODE>
__global__ __launch_bounds__(256) void k_gemm(const u16* __restrict__ A0,
                                              const u16* __restrict__ A1,
                                              const u16* __restrict__ B0,
                                              const u16* __restrict__ B1,
                                              const float* __restrict__ bias,
                                              void* __restrict__ OutP) {
  __shared__ u16 As[128 * 32];
  __shared__ u16 Bs[128 * 32];
  const int tid = threadIdx.x;
  const int w = tid >> 6, lane = tid & 63;
  const int wr = w >> 1, wc = w & 1;
  const int by = blockIdx.x, bx = blockIdx.y;       // bx = M tile, by = N tile

  // staging: 8 chunks of 16 rows x 32 cols (1KB); wave w owns chunks 2w, 2w+1
  const int c0 = w * 2, c1 = c0 + 1;
  const int lrow = lane >> 2, lcol = (lane & 3) * 8;
  const size_t a0r = (size_t)(bx * 128 + c0 * 16 + lrow) * GD + lcol;
  const size_t a1r = (size_t)(bx * 128 + c1 * 16 + lrow) * GD + lcol;
  const size_t b0r = (size_t)(by * 128 + c0 * 16 + lrow) * GD + lcol;
  const size_t b1r = (size_t)(by * 128 + c1 * 16 + lrow) * GD + lcol;
  u16* As0 = As + c0 * 512; u16* As1 = As + c1 * 512;
  u16* Bs0 = Bs + c0 * 512; u16* Bs1 = Bs + c1 * 512;

  const int aoff = (wr * 64 + (lane & 15)) * 32 + (lane >> 4) * 8;
  const int boff = (wc * 64 + (lane & 15)) * 32 + (lane >> 4) * 8;

  f32x4 acc[4][4] = {};

  for (int kt = 0; kt < 1024; kt += 32) {
    const u16* Asrc = (kt < 512) ? A0 + kt : A1 + (kt - 512);   // uniform select
    const u16* Bsrc = (kt < 512) ? B0 + kt : B1 + (kt - 512);
    gld16(Asrc + a0r, As0);
    gld16(Asrc + a1r, As1);
    gld16(Bsrc + b0r, Bs0);
    gld16(Bsrc + b1r, Bs1);
    __syncthreads();
    bf16x8 aF[4], bF[4];
    #pragma unroll
    for (int i = 0; i < 4; ++i) aF[i] = *(const bf16x8*)(As + aoff + i * 512);
    #pragma unroll
    for (int i = 0; i < 4; ++i) bF[i] = *(const bf16x8*)(Bs + boff + i * 512);
    #pragma unroll
    for (int mi = 0; mi < 4; ++mi)
      #pragma unroll
      for (int ni = 0; ni < 4; ++ni)
        acc[mi][ni] = __builtin_amdgcn_mfma_f32_16x16x32_bf16(aF[mi], bF[ni], acc[mi][ni], 0, 0, 0);
    __syncthreads();
  }

  // C/D layout: col = lane&15, row = (lane>>4)*4 + r
  const int lc = lane & 15, lr = (lane >> 4) * 4;
  const size_t r0 = (size_t)bx * 128 + wr * 64;
  const int cb = by * 128 + wc * 64;
  float bv[4];
  #pragma unroll
  for (int ni = 0; ni < 4; ++ni) bv[ni] = bias[cb + ni * 16 + lc];
  #pragma unroll
  for (int mi = 0; mi < 4; ++mi)
    #pragma unroll
    for (int ni = 0; ni < 4; ++ni)
      #pragma unroll
      for (int r = 0; r < 4; ++r) {
        float v = acc[mi][ni][r] + bv[ni];
        const size_t idx = (r0 + mi * 16 + lr + r) * GD + (cb + ni * 16 + lc);
        if (MODE == 0) {
          v = 0.5f * v * (1.0f + erff(v * 0.70710678118654752f));   // exact gelu
          ((u16*)OutP)[idx] = f2bf(v);
        } else {
          ((float*)OutP)[idx] = v;
        }
      }
}

// fused agg2 + pool: per graph g compute
//   hrb[g] = (1/48) sum_i h[i],   hab[g] = (1/48) sum_i (1/cnt_i) sum_{src->i} h[src]
__global__ __launch_bounds__(256) void k_aggh(const u16* __restrict__ h, const int* __restrict__ colOff,
                                              const int* __restrict__ colSrc,
                                              u16* __restrict__ hrb, u16* __restrict__ hab) {
  __shared__ float red[2][4][GD];                    // 16 KB
  const int g = blockIdx.x;
  const int t = threadIdx.x, w = t >> 6, lane = t & 63;
  const int f0 = lane * 8;
  float pr[8] = {}, pa[8] = {};
  for (int n = w; n < NS; n += 4) {                  // wave-cyclic over the graph's 48 nodes
    const int node = g * NS + n;
    float tmp[8];
    unpack8(*(const uint4*)(h + (size_t)node * GD + f0), tmp);
    #pragma unroll
    for (int j = 0; j < 8; ++j) pr[j] += tmp[j];
    float acc[8] = {};
    const int s0 = colOff[node], s1 = colOff[node + 1];
    for (int p = s0; p < s1; ++p) {
      unpack8(*(const uint4*)(h + (size_t)colSrc[p] * GD + f0), tmp);
      #pragma unroll
      for (int j = 0; j < 8; ++j) acc[j] += tmp[j];
    }
    const float inv = (s1 > s0) ? 1.0f / (float)(s1 - s0) : 1.0f;
    #pragma unroll
    for (int j = 0; j < 8; ++j) pa[j] += acc[j] * inv;
  }
  #pragma unroll
  for (int j = 0; j < 8; ++j) { red[0][w][f0 + j] = pr[j]; red[1][w][f0 + j] = pa[j]; }
  __syncthreads();
  const int f = t * 2;                               // 256 threads x 2 feats
  const float invS = 1.0f / (float)NS;
  float r0 = (red[0][0][f] + red[0][1][f] + red[0][2][f] + red[0][3][f]) * invS;
  float r1 = (red[0][0][f+1] + red[0][1][f+1] + red[0][2][f+1] + red[0][3][f+1]) * invS;
  float a0 = (red[1][0][f] + red[1][1][f] + red[1][2][f] + red[1][3][f]) * invS;
  float a1 = (red[1][0][f+1] + red[1][1][f+1] + red[1][2][f+1] + red[1][3][f+1]) * invS;
  unsigned pr2 = (unsigned)f2bf(r0) | ((unsigned)f2bf(r1) << 16);
  unsigned pa2 = (unsigned)f2bf(a0) | ((unsigned)f2bf(a1) << 16);
  *(unsigned*)(hrb + (size_t)g * GD + f) = pr2;
  *(unsigned*)(hab + (size_t)g * GD + f) = pa2;
}

extern "C" void kernel_launch(void* const* d_in, const int* in_sizes, int n_in,
                              void* d_out, int out_size, void* d_ws, size_t ws_size,
                              hipStream_t stream) {
  const float* x   = (const float*)d_in[0];
  const int*   ei  = (const int*)d_in[1];           // int64 in reference -> int32 on device
  const float* Wl1 = (const float*)d_in[2];
  const float* Wr1 = (const float*)d_in[3];
  const float* b1  = (const float*)d_in[4];
  const float* Wl2 = (const float*)d_in[5];
  const float* Wr2 = (const float*)d_in[6];
  const float* b2  = (const float*)d_in[7];
  float* out = (float*)d_out;
  (void)in_sizes; (void)n_in; (void)out_size; (void)ws_size;

  // ---- workspace layout ----
  int* deg     = (int*)d_ws;                 // NN
  int* cnt     = deg + NN;                   // NN
  int* rowFill = cnt + NN;                   // NN
  int* colFill = rowFill + NN;               // NN   (deg..colFill = one memset region)
  int* rowOff  = colFill + NN;               // NN+64
  int* colOff  = rowOff + NN + 64;           // NN+64
  float* dinv  = (float*)(colOff + NN + 64); // NN
  int* rowCol  = (int*)(dinv + NN);          // NE
  int* colSrc  = rowCol + NE;                // NE
  u16* WcR1    = (u16*)(colSrc + NE);        // 512*512 each
  u16* WcL1    = WcR1 + 512 * 512;
  u16* WcR2    = WcL1 + 512 * 512;
  u16* WcL2    = WcR2 + 512 * 512;
  u16* xc      = WcL2 + 512 * 512;           // NN*512 bf16
  u16* xagg    = xc + (size_t)NN * GD;       // NN*512 bf16 (dead after GEMM1)
  u16* h       = xagg + (size_t)NN * GD;     // NN*512 bf16
  u16* hrb     = xagg;                       // reuse xagg region: 1024*512
  u16* hab     = xagg + 1024 * GD;           //                    1024*512

  hipMemsetAsync(deg, 0, sizeof(int) * 4 * NN, stream);

  k_hist<<<NE / 256, 256, 0, stream>>>(ei, deg, cnt);
  k_dinv<<<NN / 256, 256, 0, stream>>>(deg, dinv);
  k_exscan<<<1, 1024, 0, stream>>>(deg, rowOff);
  k_exscan<<<1, 1024, 0, stream>>>(cnt, colOff);
  k_fill<<<NE / 256, 256, 0, stream>>>(ei, rowOff, colOff, rowFill, colFill, rowCol, colSrc);
  k_wcat<<<256, 256, 0, stream>>>(Wr1, WcR1);
  k_wcat<<<256, 256, 0, stream>>>(Wl1, WcL1);
  k_wcat<<<256, 256, 0, stream>>>(Wr2, WcR2);
  k_wcat<<<256, 256, 0, stream>>>(Wl2, WcL2);
  k_lap<<<(NN * 64) / 256, 256, 0, stream>>>(x, rowOff, rowCol, dinv, xc);
  k_aggx<<<(NN * 64) / 256, 256, 0, stream>>>(xc, colOff, colSrc, xagg);

  // h = gelu([xc|xagg] @ [Wr1|Wl1]^T + b1): M=49152, N=512, K=1024
  k_gemm<0><<<dim3(4, NN / 128), 256, 0, stream>>>(xc, xagg, WcR1, WcL1, b1, (void*)h);

  k_aggh<<<NB, 256, 0, stream>>>(h, colOff, colSrc, hrb, hab);

  // out = [hrb|hab] @ [Wr2|Wl2]^T + b2: M=1024, N=512, K=1024, f32 out
  k_gemm<1><<<dim3(4, NB / 128), 256, 0, stream>>>(hrb, hab, WcR2, WcL2, b2, (void*)out);
}

// Round 5
// 295.070 us; speedup vs baseline: 1.4110x; 1.0973x over previous
//
#include <hip/hip_runtime.h>
#include <math.h>

typedef unsigned short u16;
typedef __attribute__((ext_vector_type(8))) short bf16x8;   // 8 bf16 = 4 VGPRs (MFMA A/B frag)
typedef __attribute__((ext_vector_type(4))) float f32x4;    // MFMA C/D frag

#define NB 1024          // graphs
#define NS 48            // nodes per graph
#define ND 256           // input dim
#define NN (NB*NS)       // 49152 nodes
#define NE (4*NN)        // 196608 edges
#define GD 512           // graph_dim / feature stride everywhere

__device__ __forceinline__ void gld16(const void* g, void* l) {
  __builtin_amdgcn_global_load_lds(
      (const __attribute__((address_space(1))) void*)(void*)g,
      (__attribute__((address_space(3))) void*)l, 16, 0, 0);
}

__device__ __forceinline__ float bf2f(u16 h) {
  unsigned u = ((unsigned)h) << 16; float f; __builtin_memcpy(&f, &u, 4); return f;
}
__device__ __forceinline__ u16 f2bf(float f) {
  unsigned u; __builtin_memcpy(&u, &f, 4);
  u += 0x7fffu + ((u >> 16) & 1u);           // RNE
  return (u16)(u >> 16);
}
__device__ __forceinline__ void unpack4(uint2 v, float* f) {
  f[0]=bf2f((u16)(v.x & 0xffff)); f[1]=bf2f((u16)(v.x >> 16));
  f[2]=bf2f((u16)(v.y & 0xffff)); f[3]=bf2f((u16)(v.y >> 16));
}
__device__ __forceinline__ void unpack8(uint4 v, float* f) {
  f[0]=bf2f((u16)(v.x & 0xffff)); f[1]=bf2f((u16)(v.x >> 16));
  f[2]=bf2f((u16)(v.y & 0xffff)); f[3]=bf2f((u16)(v.y >> 16));
  f[4]=bf2f((u16)(v.z & 0xffff)); f[5]=bf2f((u16)(v.z >> 16));
  f[6]=bf2f((u16)(v.w & 0xffff)); f[7]=bf2f((u16)(v.w >> 16));
}
__device__ __forceinline__ uint4 pack8(const float* f) {
  uint4 v;
  v.x = (unsigned)f2bf(f[0]) | ((unsigned)f2bf(f[1]) << 16);
  v.y = (unsigned)f2bf(f[2]) | ((unsigned)f2bf(f[3]) << 16);
  v.z = (unsigned)f2bf(f[4]) | ((unsigned)f2bf(f[5]) << 16);
  v.w = (unsigned)f2bf(f[6]) | ((unsigned)f2bf(f[7]) << 16);
  return v;
}

// ---------- graph preprocessing (edge_index = int32 on device) ----------

__global__ void k_hist(const int* __restrict__ ei, int* __restrict__ deg, int* __restrict__ cnt) {
  int e = blockIdx.x * 256 + threadIdx.x;
  if (e < NE) {
    atomicAdd(&deg[ei[e]], 1);        // out-degree (row)
    atomicAdd(&cnt[ei[NE + e]], 1);   // in-degree  (col)
  }
}

__global__ void k_dinv(const int* __restrict__ deg, float* __restrict__ dinv) {
  int i = blockIdx.x * 256 + threadIdx.x;
  if (i < NN) dinv[i] = (deg[i] > 0) ? rsqrtf((float)deg[i]) : 0.0f;
}

// exclusive scan of NN ints, single block of 1024 threads, 48 elems/thread
__global__ void k_exscan(const int* __restrict__ in, int* __restrict__ out) {
  __shared__ int sums[1024];
  const int t = threadIdx.x;
  const int base = t * 48;
  int s = 0;
  for (int i = 0; i < 48; ++i) s += in[base + i];
  sums[t] = s;
  __syncthreads();
  for (int off = 1; off < 1024; off <<= 1) {
    int v = (t >= off) ? sums[t - off] : 0;
    __syncthreads();
    sums[t] += v;
    __syncthreads();
  }
  int run = (t == 0) ? 0 : sums[t - 1];
  for (int i = 0; i < 48; ++i) { int v = in[base + i]; out[base + i] = run; run += v; }
  if (t == 1023) out[NN] = run;
}

__global__ void k_fill(const int* __restrict__ ei,
                       const int* __restrict__ rowOff, const int* __restrict__ colOff,
                       int* __restrict__ rowFill, int* __restrict__ colFill,
                       int* __restrict__ rowCol, int* __restrict__ colSrc) {
  int e = blockIdx.x * 256 + threadIdx.x;
  if (e < NE) {
    int r = ei[e], c = ei[NE + e];
    int pr = atomicAdd(&rowFill[r], 1);
    rowCol[rowOff[r] + pr] = c;            // row-CSR: dst list per src (Laplacian)
    int pc = atomicAdd(&colFill[c], 1);
    colSrc[colOff[c] + pc] = r;            // col-CSR: src list per dst (SAGE agg)
  }
}

// convert one [512,512] f32 weight to bf16; 4 elems/thread
__global__ void k_wcat(const float* __restrict__ W, u16* __restrict__ Wc) {
  int i = (blockIdx.x * 256 + threadIdx.x) * 4;
  float4 v = *(const float4*)(W + i);
  ushort4 h; h.x = f2bf(v.x); h.y = f2bf(v.y); h.z = f2bf(v.z); h.w = f2bf(v.w);
  *(ushort4*)(Wc + i) = h;
}

// x [N,256] f32 -> xb [N,256] bf16 (8 elems/thread)
__global__ void k_x2bf(const float* __restrict__ x, u16* __restrict__ xb) {
  int i = (blockIdx.x * 256 + threadIdx.x) * 8;
  float4 v0 = *(const float4*)(x + i);
  float4 v1 = *(const float4*)(x + i + 4);
  float f[8] = {v0.x, v0.y, v0.z, v0.w, v1.x, v1.y, v1.z, v1.w};
  *(uint4*)(xb + i) = pack8(f);
}

// lap_x[i] = x[i] - dinv[i]*sum_{row-CSR} dinv[c]*x[c]; xc = [x | lap] bf16 [N,512]
// bf16 gather (half the bytes of f32) + chunk-4 ILP.
__global__ void k_lap(const u16* __restrict__ xb, const int* __restrict__ rowOff,
                      const int* __restrict__ rowCol, const float* __restrict__ dinv,
                      u16* __restrict__ xc) {
  const int gid = blockIdx.x * 256 + threadIdx.x;
  const int node = gid >> 6, lane = gid & 63;       // one wave per node, 4 feats/lane
  float xi[4]; unpack4(*(const uint2*)(xb + (size_t)node * ND + lane * 4), xi);
  float a0 = 0.f, a1 = 0.f, a2 = 0.f, a3 = 0.f;
  const int s0 = rowOff[node], s1 = rowOff[node + 1];
  for (int p = s0; p < s1; p += 4) {
    const int q1 = (p + 1 < s1) ? p + 1 : s1 - 1;
    const int q2 = (p + 2 < s1) ? p + 2 : s1 - 1;
    const int q3 = (p + 3 < s1) ? p + 3 : s1 - 1;
    const int c0 = rowCol[p], c1 = rowCol[q1], c2 = rowCol[q2], c3 = rowCol[q3];
    const float w0 = dinv[c0];
    const float w1 = (p + 1 < s1) ? dinv[c1] : 0.f;
    const float w2 = (p + 2 < s1) ? dinv[c2] : 0.f;
    const float w3 = (p + 3 < s1) ? dinv[c3] : 0.f;
    float f0[4], f1[4], f2[4], f3[4];
    unpack4(*(const uint2*)(xb + (size_t)c0 * ND + lane * 4), f0);
    unpack4(*(const uint2*)(xb + (size_t)c1 * ND + lane * 4), f1);
    unpack4(*(const uint2*)(xb + (size_t)c2 * ND + lane * 4), f2);
    unpack4(*(const uint2*)(xb + (size_t)c3 * ND + lane * 4), f3);
    a0 += w0 * f0[0] + w1 * f1[0] + w2 * f2[0] + w3 * f3[0];
    a1 += w0 * f0[1] + w1 * f1[1] + w2 * f2[1] + w3 * f3[1];
    a2 += w0 * f0[2] + w1 * f1[2] + w2 * f2[2] + w3 * f3[2];
    a3 += w0 * f0[3] + w1 * f1[3] + w2 * f2[3] + w3 * f3[3];
  }
  const float di = dinv[node];
  u16* dst = xc + (size_t)node * GD + lane * 4;
  ushort4 hx; hx.x = f2bf(xi[0]); hx.y = f2bf(xi[1]); hx.z = f2bf(xi[2]); hx.w = f2bf(xi[3]);
  *(ushort4*)dst = hx;
  ushort4 hl; hl.x = f2bf(xi[0] - di * a0); hl.y = f2bf(xi[1] - di * a1);
  hl.z = f2bf(xi[2] - di * a2); hl.w = f2bf(xi[3] - di * a3);
  *(ushort4*)(dst + ND) = hl;
}

// xagg[i] = (1/cnt_i) * sum_{src->i} xc[src]  (chunk-4 ILP)
__global__ void k_aggx(const u16* __restrict__ xc, const int* __restrict__ colOff,
                       const int* __restrict__ colSrc, u16* __restrict__ xagg) {
  const int gid = blockIdx.x * 256 + threadIdx.x;
  const int node = gid >> 6, lane = gid & 63;       // one wave per node, 8 feats/lane
  const int f0 = lane * 8;
  float acc[8] = {};
  const int s0 = colOff[node], s1 = colOff[node + 1];
  for (int p = s0; p < s1; p += 4) {
    const int q1 = (p + 1 < s1) ? p + 1 : s1 - 1;
    const int q2 = (p + 2 < s1) ? p + 2 : s1 - 1;
    const int q3 = (p + 3 < s1) ? p + 3 : s1 - 1;
    const int c0 = colSrc[p], c1 = colSrc[q1], c2 = colSrc[q2], c3 = colSrc[q3];
    const float w1 = (p + 1 < s1) ? 1.f : 0.f;
    const float w2 = (p + 2 < s1) ? 1.f : 0.f;
    const float w3 = (p + 3 < s1) ? 1.f : 0.f;
    float g0[8], g1[8], g2[8], g3[8];
    unpack8(*(const uint4*)(xc + (size_t)c0 * GD + f0), g0);
    unpack8(*(const uint4*)(xc + (size_t)c1 * GD + f0), g1);
    unpack8(*(const uint4*)(xc + (size_t)c2 * GD + f0), g2);
    unpack8(*(const uint4*)(xc + (size_t)c3 * GD + f0), g3);
    #pragma unroll
    for (int j = 0; j < 8; ++j) acc[j] += g0[j] + w1 * g1[j] + w2 * g2[j] + w3 * g3[j];
  }
  const float inv = (s1 > s0) ? 1.0f / (float)(s1 - s0) : 1.0f;
  float res[8];
  #pragma unroll
  for (int j = 0; j < 8; ++j) res[j] = acc[j] * inv;
  *(uint4*)(xagg + (size_t)node * GD + f0) = pack8(res);
}

// ---------- GEMM: Out[M,512] = A0@B0^T + A1@B1^T (+bias[, gelu]), K=512+512 ----------
// 128x128 tile, 4 waves, BK=32, global_load_lds staging.
// LDS XOR-swizzle (16B slots within 8-row stripes): source col pre-swizzled,
// fragment read k-slot XORed with the same involution -> bank-conflict-free.
// 1-D grid + XCD-bijective swizzle: same-A blocks adjacent on one XCD's L2.
// MODE 0: +bias, exact gelu, bf16 out.  MODE 1: +bias, f32 out.
template <int MODE>
__global__ __launch_bounds__(256) void k_gemm(const u16* __restrict__ A0,
                                              const u16* __restrict__ A1,
                                              const u16* __restrict__ B0,
                                              const u16* __restrict__ B1,
                                              const float* __restrict__ bias,
                                              void* __restrict__ OutP) {
  __shared__ u16 As[128 * 32];
  __shared__ u16 Bs[128 * 32];
  const int tid = threadIdx.x;
  const int w = tid >> 6, lane = tid & 63;
  const int wr = w >> 1, wc = w & 1;

  // XCD-bijective swizzle (gridDim.x % 8 == 0): XCD gets contiguous swz chunk
  const int cpx = gridDim.x >> 3;
  const int o = blockIdx.x;
  const int swz = (o & 7) * cpx + (o >> 3);
  const int bx = swz >> 2;                 // M tile
  const int by = swz & 3;                  // N tile (N=512 -> 4 tiles)

  // staging: 8 chunks of 16 rows x 32 cols; wave w owns chunks 2w, 2w+1.
  // Source col is pre-swizzled so linear LDS write == swizzled layout.
  const int c0 = w * 2, c1 = c0 + 1;
  const int lrow = lane >> 2;
  const int lcol = ((lane & 3) ^ ((lane >> 3) & 3)) * 8;   // XOR slot swizzle
  const size_t a0r = (size_t)(bx * 128 + c0 * 16 + lrow) * GD + lcol;
  const size_t a1r = (size_t)(bx * 128 + c1 * 16 + lrow) * GD + lcol;
  const size_t b0r = (size_t)(by * 128 + c0 * 16 + lrow) * GD + lcol;
  const size_t b1r = (size_t)(by * 128 + c1 * 16 + lrow) * GD + lcol;
  u16* As0 = As + c0 * 512; u16* As1 = As + c1 * 512;
  u16* Bs0 = Bs + c0 * 512; u16* Bs1 = Bs + c1 * 512;

  // fragment read: row = quad + mi*16 + (lane&15); k-slot = (lane>>4) ^ ((row>>1)&3)
  const int kslot = ((lane >> 4) ^ ((lane >> 1) & 3)) * 8;
  const int aoff = (wr * 64 + (lane & 15)) * 32 + kslot;
  const int boff = (wc * 64 + (lane & 15)) * 32 + kslot;

  f32x4 acc[4][4] = {};

  for (int kt = 0; kt < 1024; kt += 32) {
    const u16* Asrc = (kt < 512) ? A0 + kt : A1 + (kt - 512);
    const u16* Bsrc = (kt < 512) ? B0 + kt : B1 + (kt - 512);
    gld16(Asrc + a0r, As0);
    gld16(Asrc + a1r, As1);
    gld16(Bsrc + b0r, Bs0);
    gld16(Bsrc + b1r, Bs1);
    __syncthreads();
    bf16x8 aF[4], bF[4];
    #pragma unroll
    for (int i = 0; i < 4; ++i) aF[i] = *(const bf16x8*)(As + aoff + i * 512);
    #pragma unroll
    for (int i = 0; i < 4; ++i) bF[i] = *(const bf16x8*)(Bs + boff + i * 512);
    #pragma unroll
    for (int mi = 0; mi < 4; ++mi)
      #pragma unroll
      for (int ni = 0; ni < 4; ++ni)
        acc[mi][ni] = __builtin_amdgcn_mfma_f32_16x16x32_bf16(aF[mi], bF[ni], acc[mi][ni], 0, 0, 0);
    __syncthreads();
  }

  // C/D layout: col = lane&15, row = (lane>>4)*4 + r
  const int lc = lane & 15, lr = (lane >> 4) * 4;
  const size_t r0 = (size_t)bx * 128 + wr * 64;
  const int cb = by * 128 + wc * 64;
  float bv[4];
  #pragma unroll
  for (int ni = 0; ni < 4; ++ni) bv[ni] = bias[cb + ni * 16 + lc];
  #pragma unroll
  for (int mi = 0; mi < 4; ++mi)
    #pragma unroll
    for (int ni = 0; ni < 4; ++ni)
      #pragma unroll
      for (int r = 0; r < 4; ++r) {
        float v = acc[mi][ni][r] + bv[ni];
        const size_t idx = (r0 + mi * 16 + lr + r) * GD + (cb + ni * 16 + lc);
        if (MODE == 0) {
          v = 0.5f * v * (1.0f + erff(v * 0.70710678118654752f));   // exact gelu
          ((u16*)OutP)[idx] = f2bf(v);
        } else {
          ((float*)OutP)[idx] = v;
        }
      }
}

// fused agg2 + pool (chunk-4 ILP in the edge loop)
__global__ __launch_bounds__(256) void k_aggh(const u16* __restrict__ h, const int* __restrict__ colOff,
                                              const int* __restrict__ colSrc,
                                              u16* __restrict__ hrb, u16* __restrict__ hab) {
  __shared__ float red[2][4][GD];                    // 16 KB
  const int g = blockIdx.x;
  const int t = threadIdx.x, w = t >> 6, lane = t & 63;
  const int f0 = lane * 8;
  float pr[8] = {}, pa[8] = {};
  for (int n = w; n < NS; n += 4) {                  // wave-cyclic over the graph's 48 nodes
    const int node = g * NS + n;
    float tmp[8];
    unpack8(*(const uint4*)(h + (size_t)node * GD + f0), tmp);
    #pragma unroll
    for (int j = 0; j < 8; ++j) pr[j] += tmp[j];
    float acc[8] = {};
    const int s0 = colOff[node], s1 = colOff[node + 1];
    for (int p = s0; p < s1; p += 4) {
      const int q1 = (p + 1 < s1) ? p + 1 : s1 - 1;
      const int q2 = (p + 2 < s1) ? p + 2 : s1 - 1;
      const int q3 = (p + 3 < s1) ? p + 3 : s1 - 1;
      const int c0 = colSrc[p], c1 = colSrc[q1], c2 = colSrc[q2], c3 = colSrc[q3];
      const float w1 = (p + 1 < s1) ? 1.f : 0.f;
      const float w2 = (p + 2 < s1) ? 1.f : 0.f;
      const float w3 = (p + 3 < s1) ? 1.f : 0.f;
      float g0[8], g1[8], g2[8], g3[8];
      unpack8(*(const uint4*)(h + (size_t)c0 * GD + f0), g0);
      unpack8(*(const uint4*)(h + (size_t)c1 * GD + f0), g1);
      unpack8(*(const uint4*)(h + (size_t)c2 * GD + f0), g2);
      unpack8(*(const uint4*)(h + (size_t)c3 * GD + f0), g3);
      #pragma unroll
      for (int j = 0; j < 8; ++j) acc[j] += g0[j] + w1 * g1[j] + w2 * g2[j] + w3 * g3[j];
    }
    const float inv = (s1 > s0) ? 1.0f / (float)(s1 - s0) : 1.0f;
    #pragma unroll
    for (int j = 0; j < 8; ++j) pa[j] += acc[j] * inv;
  }
  #pragma unroll
  for (int j = 0; j < 8; ++j) { red[0][w][f0 + j] = pr[j]; red[1][w][f0 + j] = pa[j]; }
  __syncthreads();
  const int f = t * 2;                               // 256 threads x 2 feats
  const float invS = 1.0f / (float)NS;
  float r0 = (red[0][0][f] + red[0][1][f] + red[0][2][f] + red[0][3][f]) * invS;
  float r1 = (red[0][0][f+1] + red[0][1][f+1] + red[0][2][f+1] + red[0][3][f+1]) * invS;
  float a0 = (red[1][0][f] + red[1][1][f] + red[1][2][f] + red[1][3][f]) * invS;
  float a1 = (red[1][0][f+1] + red[1][1][f+1] + red[1][2][f+1] + red[1][3][f+1]) * invS;
  *(unsigned*)(hrb + (size_t)g * GD + f) = (unsigned)f2bf(r0) | ((unsigned)f2bf(r1) << 16);
  *(unsigned*)(hab + (size_t)g * GD + f) = (unsigned)f2bf(a0) | ((unsigned)f2bf(a1) << 16);
}

extern "C" void kernel_launch(void* const* d_in, const int* in_sizes, int n_in,
                              void* d_out, int out_size, void* d_ws, size_t ws_size,
                              hipStream_t stream) {
  const float* x   = (const float*)d_in[0];
  const int*   ei  = (const int*)d_in[1];           // int64 in reference -> int32 on device
  const float* Wl1 = (const float*)d_in[2];
  const float* Wr1 = (const float*)d_in[3];
  const float* b1  = (const float*)d_in[4];
  const float* Wl2 = (const float*)d_in[5];
  const float* Wr2 = (const float*)d_in[6];
  const float* b2  = (const float*)d_in[7];
  float* out = (float*)d_out;
  (void)in_sizes; (void)n_in; (void)out_size; (void)ws_size;

  // ---- workspace layout ----
  int* deg     = (int*)d_ws;                 // NN
  int* cnt     = deg + NN;                   // NN
  int* rowFill = cnt + NN;                   // NN
  int* colFill = rowFill + NN;               // NN   (deg..colFill = one memset region)
  int* rowOff  = colFill + NN;               // NN+64
  int* colOff  = rowOff + NN + 64;           // NN+64
  float* dinv  = (float*)(colOff + NN + 64); // NN
  int* rowCol  = (int*)(dinv + NN);          // NE
  int* colSrc  = rowCol + NE;                // NE
  u16* WcR1    = (u16*)(colSrc + NE);        // 512*512 each
  u16* WcL1    = WcR1 + 512 * 512;
  u16* WcR2    = WcL1 + 512 * 512;
  u16* WcL2    = WcR2 + 512 * 512;
  u16* xc      = WcL2 + 512 * 512;           // NN*512 bf16
  u16* xagg    = xc + (size_t)NN * GD;       // NN*512 bf16 (dead after GEMM1)
  u16* h       = xagg + (size_t)NN * GD;     // NN*512 bf16
  u16* xb      = h;                          // alias: xb [NN,256] dead before h is written
  u16* hrb     = xagg;                       // reuse xagg region: 1024*512
  u16* hab     = xagg + 1024 * GD;

  hipMemsetAsync(deg, 0, sizeof(int) * 4 * NN, stream);

  k_hist<<<NE / 256, 256, 0, stream>>>(ei, deg, cnt);
  k_dinv<<<NN / 256, 256, 0, stream>>>(deg, dinv);
  k_exscan<<<1, 1024, 0, stream>>>(deg, rowOff);
  k_exscan<<<1, 1024, 0, stream>>>(cnt, colOff);
  k_fill<<<NE / 256, 256, 0, stream>>>(ei, rowOff, colOff, rowFill, colFill, rowCol, colSrc);
  k_wcat<<<256, 256, 0, stream>>>(Wr1, WcR1);
  k_wcat<<<256, 256, 0, stream>>>(Wl1, WcL1);
  k_wcat<<<256, 256, 0, stream>>>(Wr2, WcR2);
  k_wcat<<<256, 256, 0, stream>>>(Wl2, WcL2);
  k_x2bf<<<(NN * ND) / (256 * 8), 256, 0, stream>>>(x, xb);
  k_lap<<<(NN * 64) / 256, 256, 0, stream>>>(xb, rowOff, rowCol, dinv, xc);
  k_aggx<<<(NN * 64) / 256, 256, 0, stream>>>(xc, colOff, colSrc, xagg);

  // h = gelu([xc|xagg] @ [Wr1|Wl1]^T + b1): M=49152, N=512, K=1024
  k_gemm<0><<<(NN / 128) * 4, 256, 0, stream>>>(xc, xagg, WcR1, WcL1, b1, (void*)h);

  k_aggh<<<NB, 256, 0, stream>>>(h, colOff, colSrc, hrb, hab);

  // out = [hrb|hab] @ [Wr2|Wl2]^T + b2: M=1024, N=512, K=1024, f32 out
  k_gemm<1><<<(NB / 128) * 4, 256, 0, stream>>>(hrb, hab, WcR2, WcL2, b2, (void*)out);
}

// Round 6
// 281.281 us; speedup vs baseline: 1.4801x; 1.0490x over previous
//
#include <hip/hip_runtime.h>
#include <math.h>

typedef unsigned short u16;
typedef __attribute__((ext_vector_type(8))) short bf16x8;   // 8 bf16 = 4 VGPRs (MFMA A/B frag)
typedef __attribute__((ext_vector_type(4))) float f32x4;    // MFMA C/D frag

#define NB 1024          // graphs
#define NS 48            // nodes per graph
#define ND 256           // input dim
#define NN (NB*NS)       // 49152 nodes
#define NE (4*NN)        // 196608 edges
#define GD 512           // graph_dim / feature stride everywhere

__device__ __forceinline__ void gld16(const void* g, void* l) {
  __builtin_amdgcn_global_load_lds(
      (const __attribute__((address_space(1))) void*)(void*)g,
      (__attribute__((address_space(3))) void*)l, 16, 0, 0);
}

__device__ __forceinline__ float bf2f(u16 h) {
  unsigned u = ((unsigned)h) << 16; float f; __builtin_memcpy(&f, &u, 4); return f;
}
__device__ __forceinline__ u16 f2bf(float f) {
  unsigned u; __builtin_memcpy(&u, &f, 4);
  u += 0x7fffu + ((u >> 16) & 1u);           // RNE
  return (u16)(u >> 16);
}
__device__ __forceinline__ void unpack4(uint2 v, float* f) {
  f[0]=bf2f((u16)(v.x & 0xffff)); f[1]=bf2f((u16)(v.x >> 16));
  f[2]=bf2f((u16)(v.y & 0xffff)); f[3]=bf2f((u16)(v.y >> 16));
}
__device__ __forceinline__ void unpack8(uint4 v, float* f) {
  f[0]=bf2f((u16)(v.x & 0xffff)); f[1]=bf2f((u16)(v.x >> 16));
  f[2]=bf2f((u16)(v.y & 0xffff)); f[3]=bf2f((u16)(v.y >> 16));
  f[4]=bf2f((u16)(v.z & 0xffff)); f[5]=bf2f((u16)(v.z >> 16));
  f[6]=bf2f((u16)(v.w & 0xffff)); f[7]=bf2f((u16)(v.w >> 16));
}
__device__ __forceinline__ uint4 pack8(const float* f) {
  uint4 v;
  v.x = (unsigned)f2bf(f[0]) | ((unsigned)f2bf(f[1]) << 16);
  v.y = (unsigned)f2bf(f[2]) | ((unsigned)f2bf(f[3]) << 16);
  v.z = (unsigned)f2bf(f[4]) | ((unsigned)f2bf(f[5]) << 16);
  v.w = (unsigned)f2bf(f[6]) | ((unsigned)f2bf(f[7]) << 16);
  return v;
}

// ---------- graph preprocessing (edge_index = int32 on device) ----------

__global__ void k_hist(const int* __restrict__ ei, int* __restrict__ deg, int* __restrict__ cnt) {
  int e = blockIdx.x * 256 + threadIdx.x;
  if (e < NE) {
    atomicAdd(&deg[ei[e]], 1);        // out-degree (row)
    atomicAdd(&cnt[ei[NE + e]], 1);   // in-degree  (col)
  }
}

__global__ void k_dinv(const int* __restrict__ deg, float* __restrict__ dinv) {
  int i = blockIdx.x * 256 + threadIdx.x;
  if (i < NN) dinv[i] = (deg[i] > 0) ? rsqrtf((float)deg[i]) : 0.0f;
}

// two exclusive scans of NN ints in one launch: block 0 = deg->rowOff, block 1 = cnt->colOff
__global__ void k_exscan2(const int* __restrict__ deg, const int* __restrict__ cnt,
                          int* __restrict__ rowOff, int* __restrict__ colOff) {
  __shared__ int sums[1024];
  const int* in = blockIdx.x ? cnt : deg;
  int* out = blockIdx.x ? colOff : rowOff;
  const int t = threadIdx.x;
  const int base = t * 48;
  int s = 0;
  for (int i = 0; i < 48; ++i) s += in[base + i];
  sums[t] = s;
  __syncthreads();
  for (int off = 1; off < 1024; off <<= 1) {
    int v = (t >= off) ? sums[t - off] : 0;
    __syncthreads();
    sums[t] += v;
    __syncthreads();
  }
  int run = (t == 0) ? 0 : sums[t - 1];
  for (int i = 0; i < 48; ++i) { int v = in[base + i]; out[base + i] = run; run += v; }
  if (t == 1023) out[NN] = run;
}

__global__ void k_fill(const int* __restrict__ ei,
                       const int* __restrict__ rowOff, const int* __restrict__ colOff,
                       int* __restrict__ rowFill, int* __restrict__ colFill,
                       int* __restrict__ rowCol, int* __restrict__ colSrc) {
  int e = blockIdx.x * 256 + threadIdx.x;
  if (e < NE) {
    int r = ei[e], c = ei[NE + e];
    int pr = atomicAdd(&rowFill[r], 1);
    rowCol[rowOff[r] + pr] = c;            // row-CSR: dst list per src (Laplacian)
    int pc = atomicAdd(&colFill[c], 1);
    colSrc[colOff[c] + pc] = r;            // col-CSR: src list per dst (SAGE agg)
  }
}

// all four [512,512] f32 weights -> bf16, one launch; dst = [WcR1|WcL1|WcR2|WcL2]
__global__ void k_wall(const float* __restrict__ Wr1, const float* __restrict__ Wl1,
                       const float* __restrict__ Wr2, const float* __restrict__ Wl2,
                       u16* __restrict__ Wc) {
  int i = (blockIdx.x * 256 + threadIdx.x) * 4;    // 4*262144 elems total
  int which = i >> 18;
  int off = i & 262143;
  const float* W = (which == 0) ? Wr1 : (which == 1) ? Wl1 : (which == 2) ? Wr2 : Wl2;
  float4 v = *(const float4*)(W + off);
  ushort4 h; h.x = f2bf(v.x); h.y = f2bf(v.y); h.z = f2bf(v.z); h.w = f2bf(v.w);
  *(ushort4*)(Wc + i) = h;
}

// x [N,256] f32 -> xb [N,256] bf16 (8 elems/thread)
__global__ void k_x2bf(const float* __restrict__ x, u16* __restrict__ xb) {
  int i = (blockIdx.x * 256 + threadIdx.x) * 8;
  float4 v0 = *(const float4*)(x + i);
  float4 v1 = *(const float4*)(x + i + 4);
  float f[8] = {v0.x, v0.y, v0.z, v0.w, v1.x, v1.y, v1.z, v1.w};
  *(uint4*)(xb + i) = pack8(f);
}

// lap_x[i] = x[i] - dinv[i]*sum_{row-CSR} dinv[c]*x[c]; xc = [x | lap] bf16 [N,512]
__global__ void k_lap(const u16* __restrict__ xb, const int* __restrict__ rowOff,
                      const int* __restrict__ rowCol, const float* __restrict__ dinv,
                      u16* __restrict__ xc) {
  const int gid = blockIdx.x * 256 + threadIdx.x;
  const int node = gid >> 6, lane = gid & 63;       // one wave per node, 4 feats/lane
  float xi[4]; unpack4(*(const uint2*)(xb + (size_t)node * ND + lane * 4), xi);
  float a0 = 0.f, a1 = 0.f, a2 = 0.f, a3 = 0.f;
  const int s0 = rowOff[node], s1 = rowOff[node + 1];
  for (int p = s0; p < s1; p += 4) {
    const int q1 = (p + 1 < s1) ? p + 1 : s1 - 1;
    const int q2 = (p + 2 < s1) ? p + 2 : s1 - 1;
    const int q3 = (p + 3 < s1) ? p + 3 : s1 - 1;
    const int c0 = rowCol[p], c1 = rowCol[q1], c2 = rowCol[q2], c3 = rowCol[q3];
    const float w0 = dinv[c0];
    const float w1 = (p + 1 < s1) ? dinv[c1] : 0.f;
    const float w2 = (p + 2 < s1) ? dinv[c2] : 0.f;
    const float w3 = (p + 3 < s1) ? dinv[c3] : 0.f;
    float f0[4], f1[4], f2[4], f3[4];
    unpack4(*(const uint2*)(xb + (size_t)c0 * ND + lane * 4), f0);
    unpack4(*(const uint2*)(xb + (size_t)c1 * ND + lane * 4), f1);
    unpack4(*(const uint2*)(xb + (size_t)c2 * ND + lane * 4), f2);
    unpack4(*(const uint2*)(xb + (size_t)c3 * ND + lane * 4), f3);
    a0 += w0 * f0[0] + w1 * f1[0] + w2 * f2[0] + w3 * f3[0];
    a1 += w0 * f0[1] + w1 * f1[1] + w2 * f2[1] + w3 * f3[1];
    a2 += w0 * f0[2] + w1 * f1[2] + w2 * f2[2] + w3 * f3[2];
    a3 += w0 * f0[3] + w1 * f1[3] + w2 * f2[3] + w3 * f3[3];
  }
  const float di = dinv[node];
  u16* dst = xc + (size_t)node * GD + lane * 4;
  ushort4 hx; hx.x = f2bf(xi[0]); hx.y = f2bf(xi[1]); hx.z = f2bf(xi[2]); hx.w = f2bf(xi[3]);
  *(ushort4*)dst = hx;
  ushort4 hl; hl.x = f2bf(xi[0] - di * a0); hl.y = f2bf(xi[1] - di * a1);
  hl.z = f2bf(xi[2] - di * a2); hl.w = f2bf(xi[3] - di * a3);
  *(ushort4*)(dst + ND) = hl;
}

// xagg[i] = (1/cnt_i) * sum_{src->i} xc[src]  (chunk-4 ILP)
__global__ void k_aggx(const u16* __restrict__ xc, const int* __restrict__ colOff,
                       const int* __restrict__ colSrc, u16* __restrict__ xagg) {
  const int gid = blockIdx.x * 256 + threadIdx.x;
  const int node = gid >> 6, lane = gid & 63;       // one wave per node, 8 feats/lane
  const int f0 = lane * 8;
  float acc[8] = {};
  const int s0 = colOff[node], s1 = colOff[node + 1];
  for (int p = s0; p < s1; p += 4) {
    const int q1 = (p + 1 < s1) ? p + 1 : s1 - 1;
    const int q2 = (p + 2 < s1) ? p + 2 : s1 - 1;
    const int q3 = (p + 3 < s1) ? p + 3 : s1 - 1;
    const int c0 = colSrc[p], c1 = colSrc[q1], c2 = colSrc[q2], c3 = colSrc[q3];
    const float w1 = (p + 1 < s1) ? 1.f : 0.f;
    const float w2 = (p + 2 < s1) ? 1.f : 0.f;
    const float w3 = (p + 3 < s1) ? 1.f : 0.f;
    float g0[8], g1[8], g2[8], g3[8];
    unpack8(*(const uint4*)(xc + (size_t)c0 * GD + f0), g0);
    unpack8(*(const uint4*)(xc + (size_t)c1 * GD + f0), g1);
    unpack8(*(const uint4*)(xc + (size_t)c2 * GD + f0), g2);
    unpack8(*(const uint4*)(xc + (size_t)c3 * GD + f0), g3);
    #pragma unroll
    for (int j = 0; j < 8; ++j) acc[j] += g0[j] + w1 * g1[j] + w2 * g2[j] + w3 * g3[j];
  }
  const float inv = (s1 > s0) ? 1.0f / (float)(s1 - s0) : 1.0f;
  float res[8];
  #pragma unroll
  for (int j = 0; j < 8; ++j) res[j] = acc[j] * inv;
  *(uint4*)(xagg + (size_t)node * GD + f0) = pack8(res);
}

// ---------- GEMM: Out[M,512] = A0@B0^T + A1@B1^T (+bias[, gelu]), K=512+512 ----------
// 128x128 tile, 4 waves, BK=32. Double-buffered LDS + counted vmcnt(4) (T3/T4):
// next tile's 4 global_load_lds stay in flight across the barrier; never vmcnt(0)
// in the main loop. Raw s_barrier (no compiler vmcnt(0) drain).
// LDS XOR slot-swizzle both-sides (pre-swizzled source col / swizzled frag read).
// XCD-bijective 1-D grid swizzle for A-tile L2 reuse.
template <int MODE>
__global__ __launch_bounds__(256) void k_gemm(const u16* __restrict__ A0,
                                              const u16* __restrict__ A1,
                                              const u16* __restrict__ B0,
                                              const u16* __restrict__ B1,
                                              const float* __restrict__ bias,
                                              void* __restrict__ OutP) {
  __shared__ u16 As[2][128 * 32];
  __shared__ u16 Bs[2][128 * 32];
  const int tid = threadIdx.x;
  const int w = tid >> 6, lane = tid & 63;
  const int wr = w >> 1, wc = w & 1;

  // XCD-bijective swizzle (gridDim.x % 8 == 0)
  const int cpx = gridDim.x >> 3;
  const int o = blockIdx.x;
  const int swz = (o & 7) * cpx + (o >> 3);
  const int bx = swz >> 2;                 // M tile
  const int by = swz & 3;                  // N tile (N=512 -> 4 tiles)

  // staging: 8 chunks of 16 rows x 32 cols; wave w owns chunks 2w, 2w+1.
  const int c0 = w * 2, c1 = c0 + 1;
  const int lrow = lane >> 2;
  const int lcol = ((lane & 3) ^ ((lane >> 3) & 3)) * 8;   // XOR slot swizzle
  const size_t a0r = (size_t)(bx * 128 + c0 * 16 + lrow) * GD + lcol;
  const size_t a1r = (size_t)(bx * 128 + c1 * 16 + lrow) * GD + lcol;
  const size_t b0r = (size_t)(by * 128 + c0 * 16 + lrow) * GD + lcol;
  const size_t b1r = (size_t)(by * 128 + c1 * 16 + lrow) * GD + lcol;

  // fragment read: row = quad + mi*16 + (lane&15); k-slot = (lane>>4) ^ ((row>>1)&3)
  const int kslot = ((lane >> 4) ^ ((lane >> 1) & 3)) * 8;
  const int aoff = (wr * 64 + (lane & 15)) * 32 + kslot;
  const int boff = (wc * 64 + (lane & 15)) * 32 + kslot;

  f32x4 acc[4][4] = {};

  #define STAGE(kt, buf) do {                                              \
    const u16* Asrc_ = ((kt) < 512) ? A0 + (kt) : A1 + ((kt) - 512);       \
    const u16* Bsrc_ = ((kt) < 512) ? B0 + (kt) : B1 + ((kt) - 512);       \
    gld16(Asrc_ + a0r, As[buf] + c0 * 512);                                \
    gld16(Asrc_ + a1r, As[buf] + c1 * 512);                                \
    gld16(Bsrc_ + b0r, Bs[buf] + c0 * 512);                                \
    gld16(Bsrc_ + b1r, Bs[buf] + c1 * 512);                                \
  } while (0)

  #define COMPUTE(buf) do {                                                \
    bf16x8 aF[4], bF[4];                                                   \
    _Pragma("unroll")                                                      \
    for (int i = 0; i < 4; ++i) aF[i] = *(const bf16x8*)(As[buf] + aoff + i * 512); \
    _Pragma("unroll")                                                      \
    for (int i = 0; i < 4; ++i) bF[i] = *(const bf16x8*)(Bs[buf] + boff + i * 512); \
    _Pragma("unroll")                                                      \
    for (int mi = 0; mi < 4; ++mi)                                         \
      _Pragma("unroll")                                                    \
      for (int ni = 0; ni < 4; ++ni)                                       \
        acc[mi][ni] = __builtin_amdgcn_mfma_f32_16x16x32_bf16(aF[mi], bF[ni], acc[mi][ni], 0, 0, 0); \
  } while (0)

  STAGE(0, 0);                              // prologue: tile 0 in flight
  int cur = 0;
  for (int t = 0; t < 31; ++t) {
    STAGE((t + 1) * 32, cur ^ 1);           // prefetch next tile (4 loads in flight)
    asm volatile("s_waitcnt vmcnt(4)" ::: "memory");   // own tile-t loads done
    __builtin_amdgcn_s_barrier();           // all waves' tile-t loads done
    COMPUTE(cur);
    __builtin_amdgcn_s_barrier();           // all waves done reading buf[cur]
    cur ^= 1;
  }
  asm volatile("s_waitcnt vmcnt(0)" ::: "memory");     // last tile
  __builtin_amdgcn_s_barrier();
  COMPUTE(cur);
  #undef STAGE
  #undef COMPUTE

  // C/D layout: col = lane&15, row = (lane>>4)*4 + r
  const int lc = lane & 15, lr = (lane >> 4) * 4;
  const size_t r0 = (size_t)bx * 128 + wr * 64;
  const int cb = by * 128 + wc * 64;
  float bv[4];
  #pragma unroll
  for (int ni = 0; ni < 4; ++ni) bv[ni] = bias[cb + ni * 16 + lc];
  #pragma unroll
  for (int mi = 0; mi < 4; ++mi)
    #pragma unroll
    for (int ni = 0; ni < 4; ++ni)
      #pragma unroll
      for (int r = 0; r < 4; ++r) {
        float v = acc[mi][ni][r] + bv[ni];
        const size_t idx = (r0 + mi * 16 + lr + r) * GD + (cb + ni * 16 + lc);
        if (MODE == 0) {
          v = 0.5f * v * (1.0f + erff(v * 0.70710678118654752f));   // exact gelu
          ((u16*)OutP)[idx] = f2bf(v);
        } else {
          ((float*)OutP)[idx] = v;
        }
      }
}

// fused agg2 + pool (chunk-4 ILP in the edge loop)
__global__ __launch_bounds__(256) void k_aggh(const u16* __restrict__ h, const int* __restrict__ colOff,
                                              const int* __restrict__ colSrc,
                                              u16* __restrict__ hrb, u16* __restrict__ hab) {
  __shared__ float red[2][4][GD];                    // 16 KB
  const int g = blockIdx.x;
  const int t = threadIdx.x, w = t >> 6, lane = t & 63;
  const int f0 = lane * 8;
  float pr[8] = {}, pa[8] = {};
  for (int n = w; n < NS; n += 4) {                  // wave-cyclic over the graph's 48 nodes
    const int node = g * NS + n;
    float tmp[8];
    unpack8(*(const uint4*)(h + (size_t)node * GD + f0), tmp);
    #pragma unroll
    for (int j = 0; j < 8; ++j) pr[j] += tmp[j];
    float acc[8] = {};
    const int s0 = colOff[node], s1 = colOff[node + 1];
    for (int p = s0; p < s1; p += 4) {
      const int q1 = (p + 1 < s1) ? p + 1 : s1 - 1;
      const int q2 = (p + 2 < s1) ? p + 2 : s1 - 1;
      const int q3 = (p + 3 < s1) ? p + 3 : s1 - 1;
      const int c0 = colSrc[p], c1 = colSrc[q1], c2 = colSrc[q2], c3 = colSrc[q3];
      const float w1 = (p + 1 < s1) ? 1.f : 0.f;
      const float w2 = (p + 2 < s1) ? 1.f : 0.f;
      const float w3 = (p + 3 < s1) ? 1.f : 0.f;
      float g0[8], g1[8], g2[8], g3[8];
      unpack8(*(const uint4*)(h + (size_t)c0 * GD + f0), g0);
      unpack8(*(const uint4*)(h + (size_t)c1 * GD + f0), g1);
      unpack8(*(const uint4*)(h + (size_t)c2 * GD + f0), g2);
      unpack8(*(const uint4*)(h + (size_t)c3 * GD + f0), g3);
      #pragma unroll
      for (int j = 0; j < 8; ++j) acc[j] += g0[j] + w1 * g1[j] + w2 * g2[j] + w3 * g3[j];
    }
    const float inv = (s1 > s0) ? 1.0f / (float)(s1 - s0) : 1.0f;
    #pragma unroll
    for (int j = 0; j < 8; ++j) pa[j] += acc[j] * inv;
  }
  #pragma unroll
  for (int j = 0; j < 8; ++j) { red[0][w][f0 + j] = pr[j]; red[1][w][f0 + j] = pa[j]; }
  __syncthreads();
  const int f = t * 2;                               // 256 threads x 2 feats
  const float invS = 1.0f / (float)NS;
  float r0 = (red[0][0][f] + red[0][1][f] + red[0][2][f] + red[0][3][f]) * invS;
  float r1 = (red[0][0][f+1] + red[0][1][f+1] + red[0][2][f+1] + red[0][3][f+1]) * invS;
  float a0 = (red[1][0][f] + red[1][1][f] + red[1][2][f] + red[1][3][f]) * invS;
  float a1 = (red[1][0][f+1] + red[1][1][f+1] + red[1][2][f+1] + red[1][3][f+1]) * invS;
  *(unsigned*)(hrb + (size_t)g * GD + f) = (unsigned)f2bf(r0) | ((unsigned)f2bf(r1) << 16);
  *(unsigned*)(hab + (size_t)g * GD + f) = (unsigned)f2bf(a0) | ((unsigned)f2bf(a1) << 16);
}

extern "C" void kernel_launch(void* const* d_in, const int* in_sizes, int n_in,
                              void* d_out, int out_size, void* d_ws, size_t ws_size,
                              hipStream_t stream) {
  const float* x   = (const float*)d_in[0];
  const int*   ei  = (const int*)d_in[1];           // int64 in reference -> int32 on device
  const float* Wl1 = (const float*)d_in[2];
  const float* Wr1 = (const float*)d_in[3];
  const float* b1  = (const float*)d_in[4];
  const float* Wl2 = (const float*)d_in[5];
  const float* Wr2 = (const float*)d_in[6];
  const float* b2  = (const float*)d_in[7];
  float* out = (float*)d_out;
  (void)in_sizes; (void)n_in; (void)out_size; (void)ws_size;

  // ---- workspace layout ----
  int* deg     = (int*)d_ws;                 // NN
  int* cnt     = deg + NN;                   // NN
  int* rowFill = cnt + NN;                   // NN
  int* colFill = rowFill + NN;               // NN   (deg..colFill = one memset region)
  int* rowOff  = colFill + NN;               // NN+64
  int* colOff  = rowOff + NN + 64;           // NN+64
  float* dinv  = (float*)(colOff + NN + 64); // NN
  int* rowCol  = (int*)(dinv + NN);          // NE
  int* colSrc  = rowCol + NE;                // NE
  u16* WcR1    = (u16*)(colSrc + NE);        // 512*512 each, contiguous [R1|L1|R2|L2]
  u16* WcL1    = WcR1 + 512 * 512;
  u16* WcR2    = WcL1 + 512 * 512;
  u16* WcL2    = WcR2 + 512 * 512;
  u16* xc      = WcL2 + 512 * 512;           // NN*512 bf16
  u16* xagg    = xc + (size_t)NN * GD;       // NN*512 bf16 (dead after GEMM1)
  u16* h       = xagg + (size_t)NN * GD;     // NN*512 bf16
  u16* xb      = h;                          // alias: xb [NN,256] dead before h is written
  u16* hrb     = xagg;                       // reuse xagg region: 1024*512
  u16* hab     = xagg + 1024 * GD;

  hipMemsetAsync(deg, 0, sizeof(int) * 4 * NN, stream);

  k_hist<<<NE / 256, 256, 0, stream>>>(ei, deg, cnt);
  k_dinv<<<NN / 256, 256, 0, stream>>>(deg, dinv);
  k_exscan2<<<2, 1024, 0, stream>>>(deg, cnt, rowOff, colOff);
  k_fill<<<NE / 256, 256, 0, stream>>>(ei, rowOff, colOff, rowFill, colFill, rowCol, colSrc);
  k_wall<<<1024, 256, 0, stream>>>(Wr1, Wl1, Wr2, Wl2, WcR1);
  k_x2bf<<<(NN * ND) / (256 * 8), 256, 0, stream>>>(x, xb);
  k_lap<<<(NN * 64) / 256, 256, 0, stream>>>(xb, rowOff, rowCol, dinv, xc);
  k_aggx<<<(NN * 64) / 256, 256, 0, stream>>>(xc, colOff, colSrc, xagg);

  // h = gelu([xc|xagg] @ [Wr1|Wl1]^T + b1): M=49152, N=512, K=1024
  k_gemm<0><<<(NN / 128) * 4, 256, 0, stream>>>(xc, xagg, WcR1, WcL1, b1, (void*)h);

  k_aggh<<<NB, 256, 0, stream>>>(h, colOff, colSrc, hrb, hab);

  // out = [hrb|hab] @ [Wr2|Wl2]^T + b2: M=1024, N=512, K=1024, f32 out
  k_gemm<1><<<(NB / 128) * 4, 256, 0, stream>>>(hrb, hab, WcR2, WcL2, b2, (void*)out);
}